// Round 6
// baseline (839.268 us; speedup 1.0000x reference)
//
#include <hip/hip_runtime.h>
#include <math.h>

// GPN pointer-network decode, MI355X fp32. N=128, B=512, D=128, T=16.
// R6: 1024-thread decode blocks (2 blocks/CU -> 32 resident waves = 100% cap)
// with BIT-IDENTICAL math to the verified R4 kernel. R4's per-output sums are
// (a0+a1)+(a2+a3) over four stride-4 chains; that tree maps exactly onto
// lane pairs (gates: shfl_xor(1)) and lane quads (query: shfl_xor(1),(2)).
// All other phases are R4 code verbatim under activity masks. Selection
// (argmax) therefore sees identical fp values -> identical greedy decode.

#define NREG   128
#define BATCH  512
#define DIM    128
#define TSTEPS 16
#define NEGV   (-1e9f)
#define LOG2E  1.4426950408889634f
#define CT     2.8853900817779268f   // 2*log2(e)

__device__ __forceinline__ float fexp2(float x) { return __builtin_amdgcn_exp2f(x); }
__device__ __forceinline__ float frcp(float x)  { return __builtin_amdgcn_rcpf(x); }
__device__ __forceinline__ float fast_tanh(float x) {
    return 1.f - 2.f * frcp(1.f + fexp2(CT * x));
}
__device__ __forceinline__ float fast_sig(float x) {
    return frcp(1.f + fexp2(-LOG2E * x));
}
__device__ __forceinline__ float fast_exp(float x) { return fexp2(LOG2E * x); }
__device__ __forceinline__ float fast_log(float x) {
    return __builtin_amdgcn_logf(x) * 0.6931471805599453f;
}

__device__ __forceinline__ float dot128(const float* __restrict__ wrow,
                                        const float* __restrict__ s) {
    float a0 = 0.f, a1 = 0.f, a2 = 0.f, a3 = 0.f;
#pragma unroll
    for (int k = 0; k < 128; k += 4) {
        a0 += wrow[k] * s[k];         a1 += wrow[k + 1] * s[k + 1];
        a2 += wrow[k + 2] * s[k + 2]; a3 += wrow[k + 3] * s[k + 3];
    }
    return (a0 + a1) + (a2 + a3);
}

// ---------------- K1: ALL prep in one launch (role-indexed blocks) ----------
// [0,64)   WhhP[kb][g] = float4(Whh[g][4kb..4kb+3])        (32x512 float4)
// [64,80)  gWqP[ib][o] = float4(gWq[o][4ib..4ib+3])        (32x128 float4)
// [80,82)  WihNE4[g][f] = sum_d Wih[g][d]*NE[f][d]         (512x4)
// 82       g0 = Wih@init ; bc = bih+bhh ; sumvp = sum(pv)
// 83       Q-chain: U3 = (r3W3)(r2W2)(r1W1)@NE^T (128x4);
//          Qgc = CT*gWr@U3 ; Qpc = CT*pWr@U3 ; GPQ = pWq@(gWr@U3)
// [84,148) per-b offset chain, 8 b per block: og/op/pog    (B x 128 each)
__global__ __launch_bounds__(256) void k_misc(
    const float* __restrict__ Whh, const float* __restrict__ gWq,
    const float* __restrict__ Wih, const float* __restrict__ NE,
    const float* __restrict__ init_ph,
    const float* __restrict__ bih, const float* __restrict__ bhh,
    const float* __restrict__ W1, const float* __restrict__ b1,
    const float* __restrict__ W2, const float* __restrict__ b2,
    const float* __restrict__ W3, const float* __restrict__ b3,
    const float* __restrict__ a1w, const float* __restrict__ a1b,
    const float* __restrict__ a2w, const float* __restrict__ a2b,
    const float* __restrict__ a3w, const float* __restrict__ a3b,
    const float* __restrict__ gWr, const float* __restrict__ gbr,
    const float* __restrict__ pWr, const float* __restrict__ pbr,
    const float* __restrict__ pWq, const float* __restrict__ pbq,
    const float* __restrict__ r1p, const float* __restrict__ r2p,
    const float* __restrict__ r3p,
    const float* __restrict__ pv, const float* __restrict__ data,
    float* __restrict__ WhhP, float* __restrict__ gWqP,
    float* __restrict__ WihNE4, float* __restrict__ g0,
    float* __restrict__ bc, float* __restrict__ sumvp,
    float* __restrict__ Qgc, float* __restrict__ Qpc, float* __restrict__ GPQ,
    float* __restrict__ og, float* __restrict__ op, float* __restrict__ pog)
{
    __shared__ float Ws[128 * 129];
    __shared__ float me[1024], Cv[1024], Mv[1024], Tv[1024], C2[1024], M2[1024];
    __shared__ float NEs[512], mdS[32];
    __shared__ float4 Uc[128], Vc[128], Qgu[128];

    const int blk = blockIdx.x, t = threadIdx.x;

    if (blk < 64) {
        int idx = blk * 256 + t;            // 16384: kb = idx>>9, g = idx&511
        int kb = idx >> 9, g = idx & 511;
        float4 v = *(const float4*)(Whh + g * 128 + kb * 4);
        ((float4*)WhhP)[kb * 512 + g] = v;
    } else if (blk < 80) {
        int idx = (blk - 64) * 256 + t;     // 4096: ib = idx>>7, o = idx&127
        int ib = idx >> 7, o = idx & 127;
        float4 v = *(const float4*)(gWq + o * 128 + ib * 4);
        ((float4*)gWqP)[ib * 128 + o] = v;
    } else if (blk < 82) {
        int g = (blk - 80) * 256 + t;
        float a0 = 0.f, a1 = 0.f, a2 = 0.f, a3 = 0.f;
        for (int d = 0; d < 128; d += 4) {
            float4 wv = *(const float4*)(Wih + g * 128 + d);
            float4 n0 = *(const float4*)(NE + 0 * 128 + d);
            float4 n1 = *(const float4*)(NE + 1 * 128 + d);
            float4 n2 = *(const float4*)(NE + 2 * 128 + d);
            float4 n3 = *(const float4*)(NE + 3 * 128 + d);
            a0 += wv.x * n0.x + wv.y * n0.y + wv.z * n0.z + wv.w * n0.w;
            a1 += wv.x * n1.x + wv.y * n1.y + wv.z * n1.z + wv.w * n1.w;
            a2 += wv.x * n2.x + wv.y * n2.y + wv.z * n2.z + wv.w * n2.w;
            a3 += wv.x * n3.x + wv.y * n3.y + wv.z * n3.z + wv.w * n3.w;
        }
        *(float4*)(WihNE4 + g * 4) = make_float4(a0, a1, a2, a3);
    } else if (blk == 82) {
        for (int g = t; g < 512; g += 256) {
            float acc = 0.f;
            for (int d = 0; d < 128; d += 4) {
                float4 wv = *(const float4*)(Wih + g * 128 + d);
                float4 iv = *(const float4*)(init_ph + d);
                acc += wv.x * iv.x + wv.y * iv.y + wv.z * iv.z + wv.w * iv.w;
            }
            g0[g] = acc;
            bc[g] = bih[g] + bhh[g];
        }
        if (t < 64) {
            float sv = pv[t] + pv[t + 64];
            for (int off = 32; off; off >>= 1) sv += __shfl_xor(sv, off, 64);
            if (t == 0) sumvp[0] = sv;
        }
    } else if (blk == 83) {
        if (t < 128)
            Uc[t] = make_float4(NE[t], NE[128 + t], NE[256 + t], NE[384 + t]);
        __syncthreads();
#define CH_STAGE(Wp, SRC, DST, SC)                                             \
        if (t < 128) {                                                         \
            const float* wr = (Wp) + t * 128;                                  \
            float ax = 0.f, ay = 0.f, az = 0.f, aw = 0.f;                      \
            _Pragma("unroll 8")                                                \
            for (int k = 0; k < 128; k++) {                                    \
                float w = wr[k]; float4 u = SRC[k];                            \
                ax += w * u.x; ay += w * u.y; az += w * u.z; aw += w * u.w;    \
            }                                                                  \
            float sc = (SC);                                                   \
            DST[t] = make_float4(sc * ax, sc * ay, sc * az, sc * aw);          \
        }                                                                      \
        __syncthreads();
        CH_STAGE(W1, Uc, Vc, r1p[0])     // Vc = U1
        CH_STAGE(W2, Vc, Uc, r2p[0])     // Uc = U2
        CH_STAGE(W3, Uc, Vc, r3p[0])     // Vc = U3
        CH_STAGE(gWr, Vc, Qgu, 1.f)      // Qgu = Qg
        CH_STAGE(pWr, Vc, Uc, 1.f)       // Uc = Qp
        CH_STAGE(pWq, Qgu, Vc, 1.f)      // Vc = GPQ
        if (t < 128) {
            float4 qg = Qgu[t], qp = Uc[t];
            ((float4*)Qgc)[t] = make_float4(CT * qg.x, CT * qg.y, CT * qg.z, CT * qg.w);
            ((float4*)Qpc)[t] = make_float4(CT * qp.x, CT * qp.y, CT * qp.z, CT * qp.w);
            ((float4*)GPQ)[t] = Vc[t];
        }
#undef CH_STAGE
    } else {
        const int b0 = (blk - 84) * 8;
        const float r1 = r1p[0], r2 = r2p[0], r3 = r3p[0];
#define STAGE_W(Wptr)                                                          \
        for (int i = t * 4; i < 16384; i += 1024) {                            \
            float4 v = *(const float4*)((Wptr) + i);                           \
            int oo = i >> 7, kk = i & 127;                                     \
            float* p = &Ws[oo * 129 + kk];                                     \
            p[0] = v.x; p[1] = v.y; p[2] = v.z; p[3] = v.w;                    \
        }
        if (t < 32) {
            int j = t >> 2, f = t & 3;
            float acc = 0.f;
            for (int n = 0; n < 128; n++) acc += data[n * 2048 + (b0 + j) * 4 + f];
            mdS[t] = acc * (1.f / 128.f);
        }
        for (int i = t; i < 512; i += 256) NEs[i] = NE[i];
        __syncthreads();
        for (int idx = t; idx < 1024; idx += 256) {
            int j = idx >> 7, d = idx & 127;
            me[idx] = mdS[j * 4 + 0] * NEs[d] + mdS[j * 4 + 1] * NEs[128 + d] +
                      mdS[j * 4 + 2] * NEs[256 + d] + mdS[j * 4 + 3] * NEs[384 + d];
        }
        STAGE_W(a1w);
        __syncthreads();
        {   // Tv = g1 = (1-r1)*relu(agg1@me + a1b)
            int o = t & 127, jg = t >> 7;
            for (int jj = 0; jj < 4; jj++) {
                int j = jg * 4 + jj;
                float acc = dot128(&Ws[o * 129], &me[j * 128]);
                Tv[j * 128 + o] = (1.f - r1) * fmaxf(acc + a1b[o], 0.f);
            }
        }
        __syncthreads();
        STAGE_W(W1);
        for (int idx = t; idx < 1024; idx += 256) Cv[idx] = r1 * b1[idx & 127] + Tv[idx];
        __syncthreads();
        {   // Mv = r1*(W1@me + b1) + g1
            int o = t & 127, jg = t >> 7;
            for (int jj = 0; jj < 4; jj++) {
                int j = jg * 4 + jj;
                float acc = dot128(&Ws[o * 129], &me[j * 128]);
                Mv[j * 128 + o] = r1 * (acc + b1[o]) + Tv[j * 128 + o];
            }
        }
        __syncthreads();
        STAGE_W(a2w);
        __syncthreads();
        {   // Tv = g2
            int o = t & 127, jg = t >> 7;
            for (int jj = 0; jj < 4; jj++) {
                int j = jg * 4 + jj;
                float acc = dot128(&Ws[o * 129], &Mv[j * 128]);
                Tv[j * 128 + o] = (1.f - r2) * fmaxf(acc + a2b[o], 0.f);
            }
        }
        __syncthreads();
        STAGE_W(W2);
        __syncthreads();
        {   // C2 = r2*(W2@Cv+b2)+g2 ; M2 = r2*(W2@Mv+b2)+g2
            int o = t & 127, jg = t >> 7;
            for (int jj = 0; jj < 4; jj++) {
                int j = jg * 4 + jj;
                float ac = dot128(&Ws[o * 129], &Cv[j * 128]);
                float am = dot128(&Ws[o * 129], &Mv[j * 128]);
                C2[j * 128 + o] = r2 * (ac + b2[o]) + Tv[j * 128 + o];
                M2[j * 128 + o] = r2 * (am + b2[o]) + Tv[j * 128 + o];
            }
        }
        __syncthreads();
        STAGE_W(a3w);
        __syncthreads();
        {   // Tv = g3
            int o = t & 127, jg = t >> 7;
            for (int jj = 0; jj < 4; jj++) {
                int j = jg * 4 + jj;
                float acc = dot128(&Ws[o * 129], &M2[j * 128]);
                Tv[j * 128 + o] = (1.f - r3) * fmaxf(acc + a3b[o], 0.f);
            }
        }
        __syncthreads();
        STAGE_W(W3);
        __syncthreads();
        {   // Cv = c3 = r3*(W3@C2 + b3) + g3
            int o = t & 127, jg = t >> 7;
            for (int jj = 0; jj < 4; jj++) {
                int j = jg * 4 + jj;
                float acc = dot128(&Ws[o * 129], &C2[j * 128]);
                Cv[j * 128 + o] = r3 * (acc + b3[o]) + Tv[j * 128 + o];
            }
        }
        __syncthreads();
        STAGE_W(gWr);
        __syncthreads();
        {   // Mv = og = gWr@c3 + gbr (kept for pog)
            int o = t & 127, jg = t >> 7;
            for (int jj = 0; jj < 4; jj++) {
                int j = jg * 4 + jj;
                float acc = dot128(&Ws[o * 129], &Cv[j * 128]) + gbr[o];
                Mv[j * 128 + o] = acc;
                og[(long)(b0 + j) * 128 + o] = acc;
            }
        }
        __syncthreads();
        STAGE_W(pWr);
        __syncthreads();
        {   // op = pWr@c3 + pbr
            int o = t & 127, jg = t >> 7;
            for (int jj = 0; jj < 4; jj++) {
                int j = jg * 4 + jj;
                op[(long)(b0 + j) * 128 + o] = dot128(&Ws[o * 129], &Cv[j * 128]) + pbr[o];
            }
        }
        __syncthreads();
        STAGE_W(pWq);
        __syncthreads();
        {   // pog = pWq@og + pbq
            int o = t & 127, jg = t >> 7;
            for (int jj = 0; jj < 4; jj++) {
                int j = jg * 4 + jj;
                pog[(long)(b0 + j) * 128 + o] = dot128(&Ws[o * 129], &Mv[j * 128]) + pbq[o];
            }
        }
#undef STAGE_W
    }
}

// ---------------- K2: decode, 1024 thr/block, 1 block/b, 2 blocks/CU ----------
// Bit-identical values to the R4 512-thread kernel (see header comment).
__global__ __launch_bounds__(1024, 8) void k_decode(
    const float* __restrict__ dataIn,   // [N,B,4]
    const float* __restrict__ WhhP,     // [32][512] float4 panels
    const float* __restrict__ gWqP,     // [32][128] float4 panels
    const float* __restrict__ WihNE4,   // [512][4]
    const float* __restrict__ g0,       // [512]
    const float* __restrict__ bc,       // [512]
    const float* __restrict__ Qgc, const float* __restrict__ Qpc,
    const float* __restrict__ GPQ,      // [128][4] (Qgc/Qpc pre-scaled by CT)
    const float* __restrict__ ogG, const float* __restrict__ opG,
    const float* __restrict__ pogG,     // [B][128]
    const float* __restrict__ gbq, const float* __restrict__ vgG,
    const float* __restrict__ vpG, const float* __restrict__ sumvpG,
    float* __restrict__ out)            // [T,B,N]
{
    __shared__ float4 dataS[128];
    __shared__ float4 WihS[512];
    __shared__ float4 QgcS[128], QpcS[128], GPQS[128];
    __shared__ float g0S[512], bcS[512], gateS[512];
    __shared__ float ogS[128], opS[128], pogS[128];
    __shared__ float gbqS[128], vg2S[128], vp2S[128];
    __shared__ float hS[128], cS[128], qeS[128], qepS[128];
    __shared__ float lpart[4][128];
    __shared__ int   visitedS[128];
    __shared__ int   selS;
    __shared__ float sumvpS;

    const int t = threadIdx.x;
    const int b = blockIdx.x;

    if (t < 128) {
        dataS[t] = *(const float4*)(dataIn + ((long)t * 512 + b) * 4);
        QgcS[t]  = ((const float4*)Qgc)[t];
        QpcS[t]  = ((const float4*)Qpc)[t];
        GPQS[t]  = ((const float4*)GPQ)[t];
        ogS[t]   = ogG[(long)b * 128 + t];
        opS[t]   = opG[(long)b * 128 + t];
        pogS[t]  = pogG[(long)b * 128 + t];
        gbqS[t]  = gbq[t];
        vg2S[t]  = -2.f * vgG[t];
        vp2S[t]  = -2.f * vpG[t];
        hS[t] = 0.f; cS[t] = 0.f;
        visitedS[t] = 0;
    }
    if (t < 512) {
        WihS[t] = ((const float4*)WihNE4)[t];
        g0S[t] = g0[t];
        bcS[t] = bc[t];
    }
    if (t == 0) sumvpS = sumvpG[0];
    __syncthreads();

    for (int step = 0; step < TSTEPS; step++) {
        // ---- G: lane-pair split of R4's gate dot. h2=0 owns chains a0,a1
        // (k = 4kb, 4kb+1), h2=1 owns a2,a3 (k = 4kb+2, 4kb+3). Combine
        // (ihp + partA) + partB == R4's  ihp + (a0+a1) + (a2+a3)  exactly.
        {
            int g = t >> 1, h2 = t & 1;
            const float2* wp = (const float2*)WhhP + 2 * g + h2;
            float a0 = 0.f, a1 = 0.f;
#pragma unroll
            for (int kb = 0; kb < 32; kb++) {
                float2 w = wp[(long)kb * 1024];   // panel kb, row g, half h2
                a0 += w.x * hS[4 * kb + 2 * h2];
                a1 += w.y * hS[4 * kb + 2 * h2 + 1];
            }
            float part = a0 + a1;
            float pb = __shfl_xor(part, 1);
            if (h2 == 0) {
                float ihp;
                if (step == 0) {
                    ihp = g0S[g];
                } else {
                    float4 xd = dataS[selS];
                    float4 wv = WihS[g];
                    ihp = xd.x * wv.x + xd.y * wv.y + xd.z * wv.z + xd.w * wv.w;
                }
                ihp += bcS[g];
                gateS[g] = (ihp + part) + pb;
            }
        }
        __syncthreads();
        // ---- L: LSTM pointwise (i,f,g,o) — R4 verbatim ----
        if (t < 128) {
            float ig  = fast_sig(gateS[t]);
            float fg  = fast_sig(gateS[128 + t]);
            float gg  = fast_tanh(gateS[256 + t]);
            float og_ = fast_sig(gateS[384 + t]);
            float cn = fg * cS[t] + ig * gg;
            cS[t] = cn;
            hS[t] = og_ * fast_tanh(cn);
        }
        __syncthreads();
        // ---- Q: lane-quad split of R4's query dot. Lane i owns chain a_i
        // (k = 4ib+i); tree r1=a+shfl1, r2=r1+shfl2 == (a0+a1)+(a2+a3). ----
        if (t < 512) {
            int o = t >> 2, i = t & 3;
            const float* wq = gWqP + o * 4 + i;   // panel element [ib][o].comp i
            float a = 0.f;
#pragma unroll
            for (int ib = 0; ib < 32; ib++) a += wq[(long)ib * 512] * hS[4 * ib + i];
            float r1v = a + __shfl_xor(a, 1);
            float r2v = r1v + __shfl_xor(r1v, 2);
            if (i == 0) {
                float q = r2v + gbqS[o];
                qeS[o] = CT * (q + ogS[o]);
            }
        }
        __syncthreads();
        // ---- GL: glimpse logits, R4's 4-way d-split verbatim ----
        if (t < 512) {
            int n = t & 127, q4 = t >> 7, d0 = q4 * 32;
            float4 dn = dataS[n];
            float acc = 0.f;
#pragma unroll 8
            for (int j = 0; j < 32; j++) {
                int d = d0 + j;
                float4 qg = QgcS[d];
                float x = qeS[d] + dn.x * qg.x + dn.y * qg.y + dn.z * qg.z + dn.w * qg.w;
                acc += vg2S[d] * frcp(1.f + fexp2(x));
            }
            lpart[q4][n] = acc;
        }
        __syncthreads();
        // ---- S: glimpse softmax + dp reduce + pointer query — R4 verbatim ----
        if (t < 64) {
            float l0 = visitedS[t] ? NEGV
                     : (lpart[0][t] + lpart[1][t]) + (lpart[2][t] + lpart[3][t]);
            float l1 = visitedS[t + 64] ? NEGV
                     : (lpart[0][t + 64] + lpart[1][t + 64]) + (lpart[2][t + 64] + lpart[3][t + 64]);
            float m = fmaxf(l0, l1);
            for (int off = 32; off; off >>= 1) m = fmaxf(m, __shfl_xor(m, off, 64));
            float p0 = fast_exp(l0 - m), p1 = fast_exp(l1 - m);
            float s = p0 + p1;
            float4 d0v = dataS[t], d1v = dataS[t + 64];
            float q0 = p0 * d0v.x + p1 * d1v.x;
            float q1 = p0 * d0v.y + p1 * d1v.y;
            float q2 = p0 * d0v.z + p1 * d1v.z;
            float q3 = p0 * d0v.w + p1 * d1v.w;
            for (int off = 32; off; off >>= 1) {
                s  += __shfl_xor(s, off, 64);
                q0 += __shfl_xor(q0, off, 64);
                q1 += __shfl_xor(q1, off, 64);
                q2 += __shfl_xor(q2, off, 64);
                q3 += __shfl_xor(q3, off, 64);
            }
            float inv = frcp(s);
            q0 *= inv; q1 *= inv; q2 *= inv; q3 *= inv;
            float4 gA = GPQS[t];
            qepS[t] = CT * (q0 * gA.x + q1 * gA.y + q2 * gA.z + q3 * gA.w
                            + pogS[t] + opS[t]);
            float4 gB = GPQS[t + 64];
            qepS[t + 64] = CT * (q0 * gB.x + q1 * gB.y + q2 * gB.z + q3 * gB.w
                                 + pogS[t + 64] + opS[t + 64]);
        }
        __syncthreads();
        // ---- PL: pointer logits, R4's 4-way d-split verbatim ----
        if (t < 512) {
            int n = t & 127, q4 = t >> 7, d0 = q4 * 32;
            float4 dn = dataS[n];
            float acc = 0.f;
#pragma unroll 8
            for (int j = 0; j < 32; j++) {
                int d = d0 + j;
                float4 qp = QpcS[d];
                float x = qepS[d] + dn.x * qp.x + dn.y * qp.y + dn.z * qp.z + dn.w * qp.w;
                acc += vp2S[d] * frcp(1.f + fexp2(x));
            }
            lpart[q4][n] = acc;
        }
        __syncthreads();
        // ---- P: 10*tanh, mask, log_softmax, out, argmax — R4 verbatim ----
        if (t < 64) {
            float s0 = sumvpS + (lpart[0][t] + lpart[1][t]) + (lpart[2][t] + lpart[3][t]);
            float s1 = sumvpS + (lpart[0][t + 64] + lpart[1][t + 64])
                              + (lpart[2][t + 64] + lpart[3][t + 64]);
            float l0 = visitedS[t]      ? NEGV : 10.f * fast_tanh(s0);
            float l1 = visitedS[t + 64] ? NEGV : 10.f * fast_tanh(s1);
            float m = fmaxf(l0, l1);
            for (int off = 32; off; off >>= 1) m = fmaxf(m, __shfl_xor(m, off, 64));
            float p0 = fast_exp(l0 - m), p1 = fast_exp(l1 - m);
            float s = p0 + p1;
            for (int off = 32; off; off >>= 1) s += __shfl_xor(s, off, 64);
            float lse = m + fast_log(s);
            float* outp = out + ((long)step * BATCH + b) * NREG;
            outp[t] = l0 - lse;
            outp[t + 64] = l1 - lse;
            float v; int idx;
            if (l1 > l0) { v = l1; idx = t + 64; } else { v = l0; idx = t; }
            for (int off = 32; off; off >>= 1) {
                float ov = __shfl_xor(v, off, 64);
                int   oi = __shfl_xor(idx, off, 64);
                if (ov > v || (ov == v && oi < idx)) { v = ov; idx = oi; }
            }
            if (t == 0) { selS = idx; visitedS[idx] = 1; }
        }
        __syncthreads();
    }
}

// ---------------- host launcher ----------------
extern "C" void kernel_launch(void* const* d_in, const int* in_sizes, int n_in,
                              void* d_out, int out_size, void* d_ws, size_t ws_size,
                              hipStream_t stream) {
    const float* data = (const float*)d_in[0];
    const float* NE   = (const float*)d_in[1];
    const float* init = (const float*)d_in[2];
    const float* W1w = (const float*)d_in[3];  const float* W1b = (const float*)d_in[4];
    const float* W2w = (const float*)d_in[5];  const float* W2b = (const float*)d_in[6];
    const float* W3w = (const float*)d_in[7];  const float* W3b = (const float*)d_in[8];
    const float* A1w = (const float*)d_in[9];  const float* A1b = (const float*)d_in[10];
    const float* A2w = (const float*)d_in[11]; const float* A2b = (const float*)d_in[12];
    const float* A3w = (const float*)d_in[13]; const float* A3b = (const float*)d_in[14];
    const float* r1  = (const float*)d_in[15];
    const float* r2  = (const float*)d_in[16];
    const float* r3  = (const float*)d_in[17];
    const float* Wih = (const float*)d_in[18]; const float* Whh = (const float*)d_in[19];
    const float* bih = (const float*)d_in[20]; const float* bhh = (const float*)d_in[21];
    const float* pWq = (const float*)d_in[22]; const float* pbq = (const float*)d_in[23];
    const float* pWr = (const float*)d_in[24]; const float* pbr = (const float*)d_in[25];
    const float* pv  = (const float*)d_in[26];
    const float* gWq = (const float*)d_in[27]; const float* gbq = (const float*)d_in[28];
    const float* gWr = (const float*)d_in[29]; const float* gbr = (const float*)d_in[30];
    const float* gv  = (const float*)d_in[31];
    float* out = (float*)d_out;

    float* ws     = (float*)d_ws;
    float* WhhP   = ws;                    // 65536
    float* gWqP   = WhhP + 65536;          // 16384
    float* WihNE4 = gWqP + 16384;          // 2048
    float* g0     = WihNE4 + 2048;         // 512
    float* bc     = g0 + 512;              // 512
    float* Qgc    = bc + 512;              // 512
    float* Qpc    = Qgc + 512;             // 512
    float* GPQ    = Qpc + 512;             // 512
    float* og     = GPQ + 512;             // 65536
    float* op     = og + 65536;            // 65536
    float* pog    = op + 65536;            // 65536
    float* sumvp  = pog + 65536;           // 4

    k_misc<<<148, 256, 0, stream>>>(Whh, gWq, Wih, NE, init, bih, bhh,
                                    W1w, W1b, W2w, W2b, W3w, W3b,
                                    A1w, A1b, A2w, A2b, A3w, A3b,
                                    gWr, gbr, pWr, pbr, pWq, pbq,
                                    r1, r2, r3, pv, data,
                                    WhhP, gWqP, WihNE4, g0, bc, sumvp,
                                    Qgc, Qpc, GPQ, og, op, pog);
    k_decode<<<BATCH, 1024, 0, stream>>>(data, WhhP, gWqP, WihNE4, g0, bc,
                                         Qgc, Qpc, GPQ, og, op, pog,
                                         gbq, gv, pv, sumvp, out);
}

// Round 8
// 366.408 us; speedup vs baseline: 2.2905x; 2.2905x over previous
//
#include <hip/hip_runtime.h>
#include <math.h>

// GPN pointer-network decode, MI355X fp32. N=128, B=512, D=128, T=16.
// R8 = R4 byte-for-byte revert (verified pass @ 400.7 us, absmax 0.03125).
// R5/R7 post-mortems: this problem is a 16-step argmax-feedback loop; hipcc's
// -ffp-contract=fast makes fma-contraction context-dependent, so ANY refactor
// of selection-feeding arithmetic risks a 1-ulp change that flips a greedy
// selection (absmax ~1e9). Only the R4 bit-pattern is known-good; banking it.
//
// R4: (1) whole prep in ONE kernel (role-blocks; Q-chain right-multiplied by
// NE^T is 128x4 per stage -> single block), (2) decode 512-thread blocks
// (16 waves/CU), (3) tanh loops prescaled by C=2*log2e with -2v folded into
// the accumulator FMA; glimpse sum-const dropped (softmax shift-invariant),
// (4) Whh/gWq panel-packed k-major float4 for coalesced matvec streams.

#define NREG   128
#define BATCH  512
#define DIM    128
#define TSTEPS 16
#define NEGV   (-1e9f)
#define LOG2E  1.4426950408889634f
#define CT     2.8853900817779268f   // 2*log2(e)

__device__ __forceinline__ float fexp2(float x) { return __builtin_amdgcn_exp2f(x); }
__device__ __forceinline__ float frcp(float x)  { return __builtin_amdgcn_rcpf(x); }
__device__ __forceinline__ float fast_tanh(float x) {
    return 1.f - 2.f * frcp(1.f + fexp2(CT * x));
}
__device__ __forceinline__ float fast_sig(float x) {
    return frcp(1.f + fexp2(-LOG2E * x));
}
__device__ __forceinline__ float fast_exp(float x) { return fexp2(LOG2E * x); }
__device__ __forceinline__ float fast_log(float x) {
    return __builtin_amdgcn_logf(x) * 0.6931471805599453f;
}

__device__ __forceinline__ float dot128(const float* __restrict__ wrow,
                                        const float* __restrict__ s) {
    float a0 = 0.f, a1 = 0.f, a2 = 0.f, a3 = 0.f;
#pragma unroll
    for (int k = 0; k < 128; k += 4) {
        a0 += wrow[k] * s[k];         a1 += wrow[k + 1] * s[k + 1];
        a2 += wrow[k + 2] * s[k + 2]; a3 += wrow[k + 3] * s[k + 3];
    }
    return (a0 + a1) + (a2 + a3);
}

// ---------------- K1: ALL prep in one launch (role-indexed blocks) ----------
// [0,64)   WhhP[kb][g] = float4(Whh[g][4kb..4kb+3])        (32x512 float4)
// [64,80)  gWqP[ib][o] = float4(gWq[o][4ib..4ib+3])        (32x128 float4)
// [80,82)  WihNE4[g][f] = sum_d Wih[g][d]*NE[f][d]         (512x4)
// 82       g0 = Wih@init ; bc = bih+bhh ; sumvp = sum(pv)
// 83       Q-chain: U3 = (r3W3)(r2W2)(r1W1)@NE^T (128x4);
//          Qgc = CT*gWr@U3 ; Qpc = CT*pWr@U3 ; GPQ = pWq@(gWr@U3)
// [84,148) per-b offset chain, 8 b per block: og/op/pog    (B x 128 each)
__global__ __launch_bounds__(256) void k_misc(
    const float* __restrict__ Whh, const float* __restrict__ gWq,
    const float* __restrict__ Wih, const float* __restrict__ NE,
    const float* __restrict__ init_ph,
    const float* __restrict__ bih, const float* __restrict__ bhh,
    const float* __restrict__ W1, const float* __restrict__ b1,
    const float* __restrict__ W2, const float* __restrict__ b2,
    const float* __restrict__ W3, const float* __restrict__ b3,
    const float* __restrict__ a1w, const float* __restrict__ a1b,
    const float* __restrict__ a2w, const float* __restrict__ a2b,
    const float* __restrict__ a3w, const float* __restrict__ a3b,
    const float* __restrict__ gWr, const float* __restrict__ gbr,
    const float* __restrict__ pWr, const float* __restrict__ pbr,
    const float* __restrict__ pWq, const float* __restrict__ pbq,
    const float* __restrict__ r1p, const float* __restrict__ r2p,
    const float* __restrict__ r3p,
    const float* __restrict__ pv, const float* __restrict__ data,
    float* __restrict__ WhhP, float* __restrict__ gWqP,
    float* __restrict__ WihNE4, float* __restrict__ g0,
    float* __restrict__ bc, float* __restrict__ sumvp,
    float* __restrict__ Qgc, float* __restrict__ Qpc, float* __restrict__ GPQ,
    float* __restrict__ og, float* __restrict__ op, float* __restrict__ pog)
{
    __shared__ float Ws[128 * 129];
    __shared__ float me[1024], Cv[1024], Mv[1024], Tv[1024], C2[1024], M2[1024];
    __shared__ float NEs[512], mdS[32];
    __shared__ float4 Uc[128], Vc[128], Qgu[128];

    const int blk = blockIdx.x, t = threadIdx.x;

    if (blk < 64) {
        int idx = blk * 256 + t;            // 16384: kb = idx>>9, g = idx&511
        int kb = idx >> 9, g = idx & 511;
        float4 v = *(const float4*)(Whh + g * 128 + kb * 4);
        ((float4*)WhhP)[kb * 512 + g] = v;
    } else if (blk < 80) {
        int idx = (blk - 64) * 256 + t;     // 4096: ib = idx>>7, o = idx&127
        int ib = idx >> 7, o = idx & 127;
        float4 v = *(const float4*)(gWq + o * 128 + ib * 4);
        ((float4*)gWqP)[ib * 128 + o] = v;
    } else if (blk < 82) {
        int g = (blk - 80) * 256 + t;
        float a0 = 0.f, a1 = 0.f, a2 = 0.f, a3 = 0.f;
        for (int d = 0; d < 128; d += 4) {
            float4 wv = *(const float4*)(Wih + g * 128 + d);
            float4 n0 = *(const float4*)(NE + 0 * 128 + d);
            float4 n1 = *(const float4*)(NE + 1 * 128 + d);
            float4 n2 = *(const float4*)(NE + 2 * 128 + d);
            float4 n3 = *(const float4*)(NE + 3 * 128 + d);
            a0 += wv.x * n0.x + wv.y * n0.y + wv.z * n0.z + wv.w * n0.w;
            a1 += wv.x * n1.x + wv.y * n1.y + wv.z * n1.z + wv.w * n1.w;
            a2 += wv.x * n2.x + wv.y * n2.y + wv.z * n2.z + wv.w * n2.w;
            a3 += wv.x * n3.x + wv.y * n3.y + wv.z * n3.z + wv.w * n3.w;
        }
        *(float4*)(WihNE4 + g * 4) = make_float4(a0, a1, a2, a3);
    } else if (blk == 82) {
        for (int g = t; g < 512; g += 256) {
            float acc = 0.f;
            for (int d = 0; d < 128; d += 4) {
                float4 wv = *(const float4*)(Wih + g * 128 + d);
                float4 iv = *(const float4*)(init_ph + d);
                acc += wv.x * iv.x + wv.y * iv.y + wv.z * iv.z + wv.w * iv.w;
            }
            g0[g] = acc;
            bc[g] = bih[g] + bhh[g];
        }
        if (t < 64) {
            float sv = pv[t] + pv[t + 64];
            for (int off = 32; off; off >>= 1) sv += __shfl_xor(sv, off, 64);
            if (t == 0) sumvp[0] = sv;
        }
    } else if (blk == 83) {
        // Q-chain, one block. Stage: DST[o] = sc * sum_k W[o][k]*SRC[k] (128x4)
        if (t < 128)
            Uc[t] = make_float4(NE[t], NE[128 + t], NE[256 + t], NE[384 + t]);
        __syncthreads();
#define CH_STAGE(Wp, SRC, DST, SC)                                             \
        if (t < 128) {                                                         \
            const float* wr = (Wp) + t * 128;                                  \
            float ax = 0.f, ay = 0.f, az = 0.f, aw = 0.f;                      \
            _Pragma("unroll 8")                                                \
            for (int k = 0; k < 128; k++) {                                    \
                float w = wr[k]; float4 u = SRC[k];                            \
                ax += w * u.x; ay += w * u.y; az += w * u.z; aw += w * u.w;    \
            }                                                                  \
            float sc = (SC);                                                   \
            DST[t] = make_float4(sc * ax, sc * ay, sc * az, sc * aw);          \
        }                                                                      \
        __syncthreads();
        CH_STAGE(W1, Uc, Vc, r1p[0])     // Vc = U1
        CH_STAGE(W2, Vc, Uc, r2p[0])     // Uc = U2
        CH_STAGE(W3, Uc, Vc, r3p[0])     // Vc = U3
        CH_STAGE(gWr, Vc, Qgu, 1.f)      // Qgu = Qg (unscaled)
        CH_STAGE(pWr, Vc, Uc, 1.f)       // Uc = Qp
        CH_STAGE(pWq, Qgu, Vc, 1.f)      // Vc = GPQ
        if (t < 128) {
            float4 qg = Qgu[t], qp = Uc[t];
            ((float4*)Qgc)[t] = make_float4(CT * qg.x, CT * qg.y, CT * qg.z, CT * qg.w);
            ((float4*)Qpc)[t] = make_float4(CT * qp.x, CT * qp.y, CT * qp.z, CT * qp.w);
            ((float4*)GPQ)[t] = Vc[t];
        }
#undef CH_STAGE
    } else {
        // ---- per-b offset chain, 8 b per block ----
        const int b0 = (blk - 84) * 8;
        const float r1 = r1p[0], r2 = r2p[0], r3 = r3p[0];
#define STAGE_W(Wptr)                                                          \
        for (int i = t * 4; i < 16384; i += 1024) {                            \
            float4 v = *(const float4*)((Wptr) + i);                           \
            int oo = i >> 7, kk = i & 127;                                     \
            float* p = &Ws[oo * 129 + kk];                                     \
            p[0] = v.x; p[1] = v.y; p[2] = v.z; p[3] = v.w;                    \
        }
        if (t < 32) {
            int j = t >> 2, f = t & 3;
            float acc = 0.f;
            for (int n = 0; n < 128; n++) acc += data[n * 2048 + (b0 + j) * 4 + f];
            mdS[t] = acc * (1.f / 128.f);
        }
        for (int i = t; i < 512; i += 256) NEs[i] = NE[i];
        __syncthreads();
        for (int idx = t; idx < 1024; idx += 256) {
            int j = idx >> 7, d = idx & 127;
            me[idx] = mdS[j * 4 + 0] * NEs[d] + mdS[j * 4 + 1] * NEs[128 + d] +
                      mdS[j * 4 + 2] * NEs[256 + d] + mdS[j * 4 + 3] * NEs[384 + d];
        }
        STAGE_W(a1w);
        __syncthreads();
        {   // Tv = g1 = (1-r1)*relu(agg1@me + a1b)
            int o = t & 127, jg = t >> 7;
            for (int jj = 0; jj < 4; jj++) {
                int j = jg * 4 + jj;
                float acc = dot128(&Ws[o * 129], &me[j * 128]);
                Tv[j * 128 + o] = (1.f - r1) * fmaxf(acc + a1b[o], 0.f);
            }
        }
        __syncthreads();
        STAGE_W(W1);
        for (int idx = t; idx < 1024; idx += 256) Cv[idx] = r1 * b1[idx & 127] + Tv[idx];
        __syncthreads();
        {   // Mv = r1*(W1@me + b1) + g1
            int o = t & 127, jg = t >> 7;
            for (int jj = 0; jj < 4; jj++) {
                int j = jg * 4 + jj;
                float acc = dot128(&Ws[o * 129], &me[j * 128]);
                Mv[j * 128 + o] = r1 * (acc + b1[o]) + Tv[j * 128 + o];
            }
        }
        __syncthreads();
        STAGE_W(a2w);
        __syncthreads();
        {   // Tv = g2
            int o = t & 127, jg = t >> 7;
            for (int jj = 0; jj < 4; jj++) {
                int j = jg * 4 + jj;
                float acc = dot128(&Ws[o * 129], &Mv[j * 128]);
                Tv[j * 128 + o] = (1.f - r2) * fmaxf(acc + a2b[o], 0.f);
            }
        }
        __syncthreads();
        STAGE_W(W2);
        __syncthreads();
        {   // C2 = r2*(W2@Cv+b2)+g2 ; M2 = r2*(W2@Mv+b2)+g2
            int o = t & 127, jg = t >> 7;
            for (int jj = 0; jj < 4; jj++) {
                int j = jg * 4 + jj;
                float ac = dot128(&Ws[o * 129], &Cv[j * 128]);
                float am = dot128(&Ws[o * 129], &Mv[j * 128]);
                C2[j * 128 + o] = r2 * (ac + b2[o]) + Tv[j * 128 + o];
                M2[j * 128 + o] = r2 * (am + b2[o]) + Tv[j * 128 + o];
            }
        }
        __syncthreads();
        STAGE_W(a3w);
        __syncthreads();
        {   // Tv = g3
            int o = t & 127, jg = t >> 7;
            for (int jj = 0; jj < 4; jj++) {
                int j = jg * 4 + jj;
                float acc = dot128(&Ws[o * 129], &M2[j * 128]);
                Tv[j * 128 + o] = (1.f - r3) * fmaxf(acc + a3b[o], 0.f);
            }
        }
        __syncthreads();
        STAGE_W(W3);
        __syncthreads();
        {   // Cv = c3 = r3*(W3@C2 + b3) + g3
            int o = t & 127, jg = t >> 7;
            for (int jj = 0; jj < 4; jj++) {
                int j = jg * 4 + jj;
                float acc = dot128(&Ws[o * 129], &C2[j * 128]);
                Cv[j * 128 + o] = r3 * (acc + b3[o]) + Tv[j * 128 + o];
            }
        }
        __syncthreads();
        STAGE_W(gWr);
        __syncthreads();
        {   // Mv = og = gWr@c3 + gbr (kept for pog)
            int o = t & 127, jg = t >> 7;
            for (int jj = 0; jj < 4; jj++) {
                int j = jg * 4 + jj;
                float acc = dot128(&Ws[o * 129], &Cv[j * 128]) + gbr[o];
                Mv[j * 128 + o] = acc;
                og[(long)(b0 + j) * 128 + o] = acc;
            }
        }
        __syncthreads();
        STAGE_W(pWr);
        __syncthreads();
        {   // op = pWr@c3 + pbr
            int o = t & 127, jg = t >> 7;
            for (int jj = 0; jj < 4; jj++) {
                int j = jg * 4 + jj;
                op[(long)(b0 + j) * 128 + o] = dot128(&Ws[o * 129], &Cv[j * 128]) + pbr[o];
            }
        }
        __syncthreads();
        STAGE_W(pWq);
        __syncthreads();
        {   // pog = pWq@og + pbq
            int o = t & 127, jg = t >> 7;
            for (int jj = 0; jj < 4; jj++) {
                int j = jg * 4 + jj;
                pog[(long)(b0 + j) * 128 + o] = dot128(&Ws[o * 129], &Mv[j * 128]) + pbq[o];
            }
        }
#undef STAGE_W
    }
}

// ---------------- K2: persistent decode, 512 threads / block, 1 block / b ----
__global__ __launch_bounds__(512, 4) void k_decode(
    const float* __restrict__ dataIn,   // [N,B,4]
    const float* __restrict__ WhhP,     // [32][512] float4 panels
    const float* __restrict__ gWqP,     // [32][128] float4 panels
    const float* __restrict__ WihNE4,   // [512][4]
    const float* __restrict__ g0,       // [512]
    const float* __restrict__ bc,       // [512]
    const float* __restrict__ Qgc, const float* __restrict__ Qpc,
    const float* __restrict__ GPQ,      // [128][4] each (Qgc/Qpc pre-scaled by CT)
    const float* __restrict__ ogG, const float* __restrict__ opG,
    const float* __restrict__ pogG,     // [B][128] each
    const float* __restrict__ gbq, const float* __restrict__ vgG,
    const float* __restrict__ vpG, const float* __restrict__ sumvpG,
    float* __restrict__ out)            // [T,B,N]
{
    __shared__ float4 dataS[128];
    __shared__ float4 WihS[512];
    __shared__ float4 QgcS[128], QpcS[128], GPQS[128];
    __shared__ float g0S[512], bcS[512], gatesS[512];
    __shared__ float ogS[128], opS[128], pogS[128];
    __shared__ float gbqS[128], vg2S[128], vp2S[128];
    __shared__ float hS[128], cS[128], qeS[128], qepS[128];
    __shared__ float lpart[4][128];
    __shared__ int   visitedS[128];
    __shared__ int   selS;
    __shared__ float sumvpS;

    const int t = threadIdx.x;
    const int b = blockIdx.x;

    if (t < 128) {
        dataS[t] = *(const float4*)(dataIn + ((long)t * 512 + b) * 4);
        QgcS[t]  = ((const float4*)Qgc)[t];
        QpcS[t]  = ((const float4*)Qpc)[t];
        GPQS[t]  = ((const float4*)GPQ)[t];
        ogS[t]   = ogG[(long)b * 128 + t];
        opS[t]   = opG[(long)b * 128 + t];
        pogS[t]  = pogG[(long)b * 128 + t];
        gbqS[t]  = gbq[t];
        vg2S[t]  = -2.f * vgG[t];
        vp2S[t]  = -2.f * vpG[t];
        hS[t] = 0.f; cS[t] = 0.f;
        visitedS[t] = 0;
    }
    WihS[t] = ((const float4*)WihNE4)[t];
    g0S[t] = g0[t];
    bcS[t] = bc[t];
    if (t == 0) sumvpS = sumvpG[0];
    __syncthreads();

    for (int step = 0; step < TSTEPS; step++) {
        // ---- G: one gate per thread; Whh panel stream (coalesced float4) ----
        {
            float ihp;
            if (step == 0) {
                ihp = g0S[t];
            } else {
                float4 xd = dataS[selS];
                float4 w = WihS[t];
                ihp = xd.x * w.x + xd.y * w.y + xd.z * w.z + xd.w * w.w;
            }
            ihp += bcS[t];
            const float4* wp = (const float4*)WhhP + t;
            float a0 = 0.f, a1 = 0.f, a2 = 0.f, a3 = 0.f;
#pragma unroll 8
            for (int kb = 0; kb < 32; kb++) {
                float4 w = wp[kb * 512];
                a0 += w.x * hS[4 * kb];     a1 += w.y * hS[4 * kb + 1];
                a2 += w.z * hS[4 * kb + 2]; a3 += w.w * hS[4 * kb + 3];
            }
            gatesS[t] = ihp + (a0 + a1) + (a2 + a3);
        }
        __syncthreads();
        // ---- L: LSTM pointwise (i,f,g,o) ----
        if (t < 128) {
            float ig  = fast_sig(gatesS[t]);
            float fg  = fast_sig(gatesS[128 + t]);
            float gg  = fast_tanh(gatesS[256 + t]);
            float og_ = fast_sig(gatesS[384 + t]);
            float cn = fg * cS[t] + ig * gg;
            cS[t] = cn;
            hS[t] = og_ * fast_tanh(cn);
        }
        __syncthreads();
        // ---- Q: glimpse query, full dot per o; writes prescaled qe ----
        if (t < 128) {
            const float4* wp = (const float4*)gWqP + t;
            float a0 = 0.f, a1 = 0.f, a2 = 0.f, a3 = 0.f;
#pragma unroll 8
            for (int ib = 0; ib < 32; ib++) {
                float4 w = wp[ib * 128];
                a0 += w.x * hS[4 * ib];     a1 += w.y * hS[4 * ib + 1];
                a2 += w.z * hS[4 * ib + 2]; a3 += w.w * hS[4 * ib + 3];
            }
            float q = (a0 + a1) + (a2 + a3) + gbqS[t];
            qeS[t] = CT * (q + ogS[t]);
        }
        __syncthreads();
        // ---- GL: glimpse logits, 4-way d-split; x prescaled, -2v folded ----
        {
            int n = t & 127, q4 = t >> 7, d0 = q4 * 32;
            float4 dn = dataS[n];
            float acc = 0.f;
#pragma unroll 8
            for (int j = 0; j < 32; j++) {
                int d = d0 + j;
                float4 qg = QgcS[d];
                float x = qeS[d] + dn.x * qg.x + dn.y * qg.y + dn.z * qg.z + dn.w * qg.w;
                acc += vg2S[d] * frcp(1.f + fexp2(x));
            }
            lpart[q4][n] = acc;
        }
        __syncthreads();
        // ---- S: glimpse softmax + dp reduce + pointer query (1 wave) ----
        if (t < 64) {
            float l0 = visitedS[t] ? NEGV
                     : (lpart[0][t] + lpart[1][t]) + (lpart[2][t] + lpart[3][t]);
            float l1 = visitedS[t + 64] ? NEGV
                     : (lpart[0][t + 64] + lpart[1][t + 64]) + (lpart[2][t + 64] + lpart[3][t + 64]);
            float m = fmaxf(l0, l1);
            for (int off = 32; off; off >>= 1) m = fmaxf(m, __shfl_xor(m, off, 64));
            float p0 = fast_exp(l0 - m), p1 = fast_exp(l1 - m);
            float s = p0 + p1;
            float4 d0v = dataS[t], d1v = dataS[t + 64];
            float q0 = p0 * d0v.x + p1 * d1v.x;
            float q1 = p0 * d0v.y + p1 * d1v.y;
            float q2 = p0 * d0v.z + p1 * d1v.z;
            float q3 = p0 * d0v.w + p1 * d1v.w;
            for (int off = 32; off; off >>= 1) {
                s  += __shfl_xor(s, off, 64);
                q0 += __shfl_xor(q0, off, 64);
                q1 += __shfl_xor(q1, off, 64);
                q2 += __shfl_xor(q2, off, 64);
                q3 += __shfl_xor(q3, off, 64);
            }
            float inv = frcp(s);
            q0 *= inv; q1 *= inv; q2 *= inv; q3 *= inv;
            float4 gA = GPQS[t];
            qepS[t] = CT * (q0 * gA.x + q1 * gA.y + q2 * gA.z + q3 * gA.w
                            + pogS[t] + opS[t]);
            float4 gB = GPQS[t + 64];
            qepS[t + 64] = CT * (q0 * gB.x + q1 * gB.y + q2 * gB.z + q3 * gB.w
                                 + pogS[t + 64] + opS[t + 64]);
        }
        __syncthreads();
        // ---- PL: pointer logits ----
        {
            int n = t & 127, q4 = t >> 7, d0 = q4 * 32;
            float4 dn = dataS[n];
            float acc = 0.f;
#pragma unroll 8
            for (int j = 0; j < 32; j++) {
                int d = d0 + j;
                float4 qp = QpcS[d];
                float x = qepS[d] + dn.x * qp.x + dn.y * qp.y + dn.z * qp.z + dn.w * qp.w;
                acc += vp2S[d] * frcp(1.f + fexp2(x));
            }
            lpart[q4][n] = acc;
        }
        __syncthreads();
        // ---- P: 10*tanh, mask, log_softmax, out, argmax (1 wave) ----
        if (t < 64) {
            float s0 = sumvpS + (lpart[0][t] + lpart[1][t]) + (lpart[2][t] + lpart[3][t]);
            float s1 = sumvpS + (lpart[0][t + 64] + lpart[1][t + 64])
                              + (lpart[2][t + 64] + lpart[3][t + 64]);
            float l0 = visitedS[t]      ? NEGV : 10.f * fast_tanh(s0);
            float l1 = visitedS[t + 64] ? NEGV : 10.f * fast_tanh(s1);
            float m = fmaxf(l0, l1);
            for (int off = 32; off; off >>= 1) m = fmaxf(m, __shfl_xor(m, off, 64));
            float p0 = fast_exp(l0 - m), p1 = fast_exp(l1 - m);
            float s = p0 + p1;
            for (int off = 32; off; off >>= 1) s += __shfl_xor(s, off, 64);
            float lse = m + fast_log(s);
            float* outp = out + ((long)step * BATCH + b) * NREG;
            outp[t] = l0 - lse;
            outp[t + 64] = l1 - lse;
            float v; int idx;
            if (l1 > l0) { v = l1; idx = t + 64; } else { v = l0; idx = t; }
            for (int off = 32; off; off >>= 1) {
                float ov = __shfl_xor(v, off, 64);
                int   oi = __shfl_xor(idx, off, 64);
                if (ov > v || (ov == v && oi < idx)) { v = ov; idx = oi; }
            }
            if (t == 0) { selS = idx; visitedS[idx] = 1; }
        }
        __syncthreads();
    }
}

// ---------------- host launcher ----------------
extern "C" void kernel_launch(void* const* d_in, const int* in_sizes, int n_in,
                              void* d_out, int out_size, void* d_ws, size_t ws_size,
                              hipStream_t stream) {
    const float* data = (const float*)d_in[0];
    const float* NE   = (const float*)d_in[1];
    const float* init = (const float*)d_in[2];
    const float* W1w = (const float*)d_in[3];  const float* W1b = (const float*)d_in[4];
    const float* W2w = (const float*)d_in[5];  const float* W2b = (const float*)d_in[6];
    const float* W3w = (const float*)d_in[7];  const float* W3b = (const float*)d_in[8];
    const float* A1w = (const float*)d_in[9];  const float* A1b = (const float*)d_in[10];
    const float* A2w = (const float*)d_in[11]; const float* A2b = (const float*)d_in[12];
    const float* A3w = (const float*)d_in[13]; const float* A3b = (const float*)d_in[14];
    const float* r1  = (const float*)d_in[15];
    const float* r2  = (const float*)d_in[16];
    const float* r3  = (const float*)d_in[17];
    const float* Wih = (const float*)d_in[18]; const float* Whh = (const float*)d_in[19];
    const float* bih = (const float*)d_in[20]; const float* bhh = (const float*)d_in[21];
    const float* pWq = (const float*)d_in[22]; const float* pbq = (const float*)d_in[23];
    const float* pWr = (const float*)d_in[24]; const float* pbr = (const float*)d_in[25];
    const float* pv  = (const float*)d_in[26];
    const float* gWq = (const float*)d_in[27]; const float* gbq = (const float*)d_in[28];
    const float* gWr = (const float*)d_in[29]; const float* gbr = (const float*)d_in[30];
    const float* gv  = (const float*)d_in[31];
    float* out = (float*)d_out;

    float* ws     = (float*)d_ws;
    float* WhhP   = ws;                    // 65536
    float* gWqP   = WhhP + 65536;          // 16384
    float* WihNE4 = gWqP + 16384;          // 2048
    float* g0     = WihNE4 + 2048;         // 512
    float* bc     = g0 + 512;              // 512
    float* Qgc    = bc + 512;              // 512
    float* Qpc    = Qgc + 512;             // 512
    float* GPQ    = Qpc + 512;             // 512
    float* og     = GPQ + 512;             // 65536
    float* op     = og + 65536;            // 65536
    float* pog    = op + 65536;            // 65536
    float* sumvp  = pog + 65536;           // 4

    k_misc<<<148, 256, 0, stream>>>(Whh, gWq, Wih, NE, init, bih, bhh,
                                    W1w, W1b, W2w, W2b, W3w, W3b,
                                    A1w, A1b, A2w, A2b, A3w, A3b,
                                    gWr, gbr, pWr, pbr, pWq, pbq,
                                    r1, r2, r3, pv, data,
                                    WhhP, gWqP, WihNE4, g0, bc, sumvp,
                                    Qgc, Qpc, GPQ, og, op, pog);
    k_decode<<<BATCH, 512, 0, stream>>>(data, WhhP, gWqP, WihNE4, g0, bc,
                                        Qgc, Qpc, GPQ, og, op, pog,
                                        gbq, gv, pv, sumvp, out);
}